// Round 9
// baseline (246.620 us; speedup 1.0000x reference)
//
#include <hip/hip_runtime.h>
#include <hip/hip_cooperative_groups.h>

namespace cg = cooperative_groups;

#define Bb 4
#define AT 384
#define NBR 24
#define FEAT 128
#define ROWQ (FEAT / 4)              // 32 float4 per feature row
#define TILEQ (NBR * ROWQ)           // 768 float4 per (b,a,j) tile / (b,a) panel
#define NTILES (Bb * AT * NBR)       // 36864
#define OUTQ ((unsigned)NTILES * TILEQ)  // 28,311,552 float4
#define COOP_BLOCKS 1024

typedef float vfloat4 __attribute__((ext_vector_type(4)));

// One cooperative dispatch.
// Phase 1: pure dependency-free zero-fill of the entire output (structurally
//          identical to rocclr fillBufferAligned, proven 6.7-6.9 TB/s).
// grid.sync()
// Phase 2: mask + sparse scatter of the ~0.2% matched rows over the zeros.
__global__ __launch_bounds__(256) void fused_kernel(
    const vfloat4* __restrict__ edge,   // (B, AT, NBR, FEAT) as float4
    const int*     __restrict__ nbr,    // (B, AT, NBR)
    const float*   __restrict__ cell,   // (B, AT, NBR, 3)
    vfloat4*       __restrict__ out)    // (B, AT, NBR_j, NBR_i, FEAT)
{
    const int t = threadIdx.x;

    // ---------- phase 1: pure fill ----------
    {
        const vfloat4 zero = (vfloat4)(0.f);
        const unsigned stride = gridDim.x * 256u;
        for (unsigned q = blockIdx.x * 256u + t; q < OUTQ; q += stride)
            out[q] = zero;
    }

    cg::this_grid().sync();

    // ---------- phase 2: mask + scatter ----------
    __shared__ int   s_nbr[NBR];
    __shared__ float s_cell[NBR][3];
    __shared__ int   s_nbrj[NBR][NBR];
    __shared__ float s_cellj[NBR][NBR][3];
    __shared__ int   s_list[NBR * NBR];   // packed (j<<5)|i
    __shared__ int   s_cnt;

    for (int ba = blockIdx.x; ba < Bb * AT; ba += gridDim.x) {
        const int b = ba / AT;

        if (t == 0) s_cnt = 0;
        if (t < NBR) {
            s_nbr[t]     = nbr[ba * NBR + t];
            s_cell[t][0] = cell[(ba * NBR + t) * 3 + 0];
            s_cell[t][1] = cell[(ba * NBR + t) * 3 + 1];
            s_cell[t][2] = cell[(ba * NBR + t) * 3 + 2];
        }
        __syncthreads();

        for (int q = t; q < NBR * NBR; q += 256) {
            const int j = q / NBR;
            const int k = q % NBR;
            const int base = (b * AT + s_nbr[j]) * NBR + k;
            s_nbrj[j][k]     = nbr[base];
            s_cellj[j][k][0] = cell[base * 3 + 0];
            s_cellj[j][k][1] = cell[base * 3 + 1];
            s_cellj[j][k][2] = cell[base * 3 + 2];
        }
        __syncthreads();

        for (int p = t; p < NBR * NBR; p += 256) {
            const int j = p / NBR;
            const int i = p % NBR;
            if (i != j) {
                const int   myidx = s_nbr[i];
                const float c0 = s_cell[i][0];
                const float c1 = s_cell[i][1];
                const float c2 = s_cell[i][2];
                int m = 0;
                #pragma unroll
                for (int k = 0; k < NBR; ++k) {
                    if (s_nbrj[j][k] == myidx &&
                        s_cellj[j][k][0] == c0 &&
                        s_cellj[j][k][1] == c1 &&
                        s_cellj[j][k][2] == c2) { m = 1; }
                }
                if (m) {
                    const int slot = atomicAdd(&s_cnt, 1);
                    s_list[slot] = (j << 5) | i;
                }
            }
        }
        __syncthreads();

        const int cnt  = s_cnt;
        const int g    = t >> 5;
        const int lane = t & 31;
        const vfloat4* __restrict__ erow = edge + (size_t)ba * TILEQ;
        for (int p = g; p < cnt; p += 8) {
            const int ji = s_list[p];
            const int j  = ji >> 5;
            const int i  = ji & 31;
            out[((size_t)(ba * NBR + j) * NBR + i) * ROWQ + lane] =
                erow[i * ROWQ + lane];
        }
        __syncthreads();
    }
}

// ---------------- Fallback: R1 monolithic (proven 88.3 us) ----------------
__global__ __launch_bounds__(256) void mono_kernel(
    const float* __restrict__ edge,
    const int*   __restrict__ nbr,
    const float* __restrict__ cell,
    float*       __restrict__ out)
{
    const int blk = blockIdx.x;
    const int j   = blk % NBR;
    const int ba  = blk / NBR;
    const int b   = ba / AT;

    __shared__ int   s_nbrj[NBR];
    __shared__ float s_cellj[NBR][3];
    __shared__ int   s_mask[NBR];

    const int t = threadIdx.x;
    const int jatom = nbr[ba * NBR + j];

    if (t < NBR) {
        const int base = (b * AT + jatom) * NBR + t;
        s_nbrj[t]     = nbr[base];
        s_cellj[t][0] = cell[base * 3 + 0];
        s_cellj[t][1] = cell[base * 3 + 1];
        s_cellj[t][2] = cell[base * 3 + 2];
    }
    __syncthreads();

    if (t < NBR) {
        int m = 0;
        if (t != j) {
            const int   myidx = nbr[ba * NBR + t];
            const float c0 = cell[(ba * NBR + t) * 3 + 0];
            const float c1 = cell[(ba * NBR + t) * 3 + 1];
            const float c2 = cell[(ba * NBR + t) * 3 + 2];
            #pragma unroll
            for (int k = 0; k < NBR; ++k) {
                if (s_nbrj[k] == myidx &&
                    s_cellj[k][0] == c0 &&
                    s_cellj[k][1] == c1 &&
                    s_cellj[k][2] == c2) { m = 1; }
            }
        }
        s_mask[t] = m;
    }
    __syncthreads();

    const float4* __restrict__ erow = (const float4*)(edge + (size_t)ba * NBR * FEAT);
    float4*       __restrict__ orow = (float4*)(out + (size_t)blk * NBR * FEAT);
    const float4 zero = make_float4(0.f, 0.f, 0.f, 0.f);
    #pragma unroll
    for (int it = 0; it < 3; ++it) {
        const int q = t + it * 256;
        const int i = q >> 5;
        float4 v = zero;
        if (s_mask[i]) v = erow[q];
        orow[q] = v;
    }
}

extern "C" void kernel_launch(void* const* d_in, const int* in_sizes, int n_in,
                              void* d_out, int out_size, void* d_ws, size_t ws_size,
                              hipStream_t stream) {
    const vfloat4* edge = (const vfloat4*)d_in[0];
    const int*     nbr  = (const int*)d_in[1];
    const float*   cell = (const float*)d_in[2];
    vfloat4*       out  = (vfloat4*)d_out;

    void* args[] = { (void*)&edge, (void*)&nbr, (void*)&cell, (void*)&out };
    hipError_t err = hipLaunchCooperativeKernel(
        reinterpret_cast<void*>(fused_kernel),
        dim3(COOP_BLOCKS), dim3(256), args, 0, stream);

    if (err != hipSuccess) {
        // cooperative launch unavailable -> proven monolithic path
        mono_kernel<<<NTILES, 256, 0, stream>>>(
            (const float*)edge, nbr, cell, (float*)out);
    }
}